// Round 5
// baseline (16.852 us; speedup 1.0000x reference)
//
#include <hip/hip_runtime.h>
#include <float.h>

#define BB 256
#define VV 10475
#define RR 75
#define KK 5
#define RKN (RR * KK)     // 375 points per array per batch
#define NOUT (RR * RR)    // 5625 entries per batch
#define TPB 384           // 6 waves per block, 2 blocks per batch

// Split: block h=0 -> rows 0..38 (13 row-tiles), h=1 -> rows 39..74 (12 row-tiles)
#define NROWS0 39
#define NROWS1 36

__global__ __launch_bounds__(TPB) void ContactMap_47691316854895_kernel(
    const float* __restrict__ v1,
    const float* __restrict__ v2,
    const int* __restrict__ rid,
    float* __restrict__ out)
{
    __shared__ float4 g1s[NROWS0 * KK];  // up to 195 A-points for this half
    __shared__ float4 g2s[RKN];          // all 375 B-points

    const int b = blockIdx.x;
    const int h = blockIdx.y;
    const int tid = threadIdx.x;

    const int r0    = h ? NROWS0 : 0;
    const int nrows = h ? NROWS1 : NROWS0;
    const int nA    = nrows * KK;        // 195 or 180

    const float* v1b = v1 + (size_t)b * VV * 3;
    const float* v2b = v2 + (size_t)b * VV * 3;

    // Gather: nA A-points (this half's rows) + all 375 B-points.
    for (int t = tid; t < nA + RKN; t += TPB) {
        if (t < nA) {
            const int idx = rid[r0 * KK + t];
            const float* p = v1b + (size_t)idx * 3;
            g1s[t] = make_float4(p[0], p[1], p[2], 0.0f);
        } else {
            const int u = t - nA;
            const int idx = rid[u];
            const float* p = v2b + (size_t)idx * 3;
            g2s[u] = make_float4(p[0], p[1], p[2], 0.0f);
        }
    }
    __syncthreads();

    const int nrowtiles = nrows / 3;         // 13 or 12
    const int ntile = nrowtiles * 25;        // 325 or 300 active compute threads
    if (tid >= ntile) return;

    const int i0l = (tid / 25) * 3;          // local row base within this half
    const int j0  = (tid % 25) * 3;

    // Hoist the 3 a-residues (15 points) into registers.
    float ax[3][KK], ay[3][KK], az[3][KK];
#pragma unroll
    for (int ii = 0; ii < 3; ++ii) {
#pragma unroll
        for (int p = 0; p < KK; ++p) {
            const float4 a = g1s[(i0l + ii) * KK + p];
            ax[ii][p] = a.x; ay[ii][p] = a.y; az[ii][p] = a.z;
        }
    }

    float* outb = out + (size_t)b * NOUT;

#pragma unroll
    for (int jj = 0; jj < 3; ++jj) {
        float bx[KK], by[KK], bz[KK];
#pragma unroll
        for (int q = 0; q < KK; ++q) {
            const float4 v = g2s[(j0 + jj) * KK + q];
            bx[q] = v.x; by[q] = v.y; bz[q] = v.z;
        }
#pragma unroll
        for (int ii = 0; ii < 3; ++ii) {
            float best = FLT_MAX;
#pragma unroll
            for (int p = 0; p < KK; ++p) {
#pragma unroll
                for (int q = 0; q < KK; ++q) {
                    const float dx = ax[ii][p] - bx[q];
                    const float dy = ay[ii][p] - by[q];
                    const float dz = az[ii][p] - bz[q];
                    const float d2 = dx * dx + dy * dy + dz * dz;
                    best = fminf(best, d2);
                }
            }
            outb[(size_t)(r0 + i0l + ii) * RR + (j0 + jj)] = sqrtf(best);
        }
    }
}

extern "C" void kernel_launch(void* const* d_in, const int* in_sizes, int n_in,
                              void* d_out, int out_size, void* d_ws, size_t ws_size,
                              hipStream_t stream) {
    const float* v1 = (const float*)d_in[0];
    const float* v2 = (const float*)d_in[1];
    const int* rid = (const int*)d_in[2];
    float* out = (float*)d_out;

    ContactMap_47691316854895_kernel<<<dim3(BB, 2), dim3(TPB), 0, stream>>>(v1, v2, rid, out);
}

// Round 6
// 13.262 us; speedup vs baseline: 1.2707x; 1.2707x over previous
//
#include <hip/hip_runtime.h>
#include <float.h>

#define BB 256
#define VV 10475
#define RR 75
#define KK 5
#define RKN (RR * KK)     // 375 gathered points per array
#define NOUT (RR * RR)    // 5625 entries per batch
#define TI 3
#define TJ 3
#define NTI (RR / TI)     // 25
#define NTJ (RR / TJ)     // 25
#define NTILE (NTI * NTJ) // 625 active compute threads
#define TPB 768           // 12 waves: 750 gather threads, 625 compute threads

__global__ __launch_bounds__(TPB) void ContactMap_47691316854895_kernel(
    const float* __restrict__ v1,
    const float* __restrict__ v2,
    const int* __restrict__ rid,
    float* __restrict__ out)
{
    // .xyz = point coords, .w = |point|^2 (computed once at gather time)
    __shared__ float4 g1s[RKN];   // 6 KB
    __shared__ float4 g2s[RKN];   // 6 KB

    const int b = blockIdx.x;
    const int tid = threadIdx.x;

    // Split gather: threads 0-374 -> v1, 375-749 -> v2.
    // 3 dependent scattered loads per thread; squared norm fused here.
    if (tid < RKN) {
        const int idx = rid[tid];
        const float* p = v1 + ((size_t)b * VV + idx) * 3;
        const float x = p[0], y = p[1], z = p[2];
        g1s[tid] = make_float4(x, y, z, x * x + y * y + z * z);
    } else if (tid < 2 * RKN) {
        const int t = tid - RKN;
        const int idx = rid[t];
        const float* p = v2 + ((size_t)b * VV + idx) * 3;
        const float x = p[0], y = p[1], z = p[2];
        g2s[t] = make_float4(x, y, z, x * x + y * y + z * z);
    }
    __syncthreads();

    if (tid >= NTILE) return;

    const int i0 = (tid / NTJ) * TI;
    const int j0 = (tid % NTJ) * TJ;

    // Hoist the 3 a-residues (15 points + norms) into registers.
    float ax[TI][KK], ay[TI][KK], az[TI][KK], aw[TI][KK];
#pragma unroll
    for (int ii = 0; ii < TI; ++ii) {
#pragma unroll
        for (int p = 0; p < KK; ++p) {
            const float4 a = g1s[(i0 + ii) * KK + p];
            ax[ii][p] = a.x; ay[ii][p] = a.y; az[ii][p] = a.z; aw[ii][p] = a.w;
        }
    }

    float* outb = out + (size_t)b * NOUT;

#pragma unroll
    for (int jj = 0; jj < TJ; ++jj) {
        float bx[KK], by[KK], bz[KK], bw[KK];
#pragma unroll
        for (int q = 0; q < KK; ++q) {
            const float4 v = g2s[(j0 + jj) * KK + q];
            bx[q] = v.x; by[q] = v.y; bz[q] = v.z; bw[q] = v.w;
        }
#pragma unroll
        for (int ii = 0; ii < TI; ++ii) {
            float best = FLT_MAX;
#pragma unroll
            for (int p = 0; p < KK; ++p) {
                float bq = FLT_MAX;
#pragma unroll
                for (int q = 0; q < KK; ++q) {
                    float zz = ax[ii][p] * bx[q];
                    zz = fmaf(ay[ii][p], by[q], zz);
                    zz = fmaf(az[ii][p], bz[q], zz);
                    // ry - 2*z  (rx added once per p below)
                    bq = fminf(bq, fmaf(-2.0f, zz, bw[q]));
                }
                best = fminf(best, aw[ii][p] + bq);
            }
            outb[(size_t)(i0 + ii) * RR + (j0 + jj)] = sqrtf(fmaxf(best, 0.0f));
        }
    }
}

extern "C" void kernel_launch(void* const* d_in, const int* in_sizes, int n_in,
                              void* d_out, int out_size, void* d_ws, size_t ws_size,
                              hipStream_t stream) {
    const float* v1 = (const float*)d_in[0];
    const float* v2 = (const float*)d_in[1];
    const int* rid = (const int*)d_in[2];
    float* out = (float*)d_out;

    ContactMap_47691316854895_kernel<<<dim3(BB), dim3(TPB), 0, stream>>>(v1, v2, rid, out);
}